// Round 7
// baseline (459.140 us; speedup 1.0000x reference)
//
#include <hip/hip_runtime.h>

#define B_ 256
#define T_ 1024
#define F_ 64
#define H_ 32
#define V_ 13
#define K4 128   // 4*H

typedef float f32x4 __attribute__((ext_vector_type(4)));

__device__ __forceinline__ void fma4(float4& acc, float s, const float4& wv) {
  acc.x = fmaf(s, wv.x, acc.x);
  acc.y = fmaf(s, wv.y, acc.y);
  acc.z = fmaf(s, wv.z, acc.z);
  acc.w = fmaf(s, wv.w, acc.w);
}

// ---------------- Kernel A: xz = x @ W + b  ([B*T,64] @ [64,128]) ----------------
__global__ __launch_bounds__(256, 2) void xz_gemm(const float* __restrict__ x,
                                                  const float* __restrict__ W,
                                                  const float* __restrict__ bias,
                                                  float* __restrict__ xz) {
  __shared__ float4 Ws4[F_ * 32];    // W[f][0..127] as 32 float4 per f   (32 KB)
  __shared__ float4 Xs4[128 * 16];   // x[r][0..63]  as 16 float4 per row (32 KB)

  const float4* W4 = (const float4*)W;
  for (int i = threadIdx.x; i < F_ * 32; i += 256) Ws4[i] = W4[i];
  const int row0 = blockIdx.x * 128;
  const float4* X4 = (const float4*)(x + (size_t)row0 * F_);
  for (int i = threadIdx.x; i < 128 * 16; i += 256) Xs4[i] = X4[i];
  __syncthreads();

  const int cg = threadIdx.x & 31;   // column group: cols 4*cg .. 4*cg+3
  const int rs = threadIdx.x >> 5;   // row slot 0..7; rows rs + 8*rr
  const float4 bv = ((const float4*)bias)[cg];

  float4 acc[16];
#pragma unroll
  for (int rr = 0; rr < 16; ++rr) acc[rr] = bv;

#pragma unroll
  for (int fg = 0; fg < 16; ++fg) {                 // 4 f-values per iteration
    float4 w0 = Ws4[(4 * fg + 0) * 32 + cg];
    float4 w1 = Ws4[(4 * fg + 1) * 32 + cg];
    float4 w2 = Ws4[(4 * fg + 2) * 32 + cg];
    float4 w3 = Ws4[(4 * fg + 3) * 32 + cg];
#pragma unroll
    for (int rr = 0; rr < 16; ++rr) {
      float4 xv = Xs4[(rs + 8 * rr) * 16 + fg];
      fma4(acc[rr], xv.x, w0);
      fma4(acc[rr], xv.y, w1);
      fma4(acc[rr], xv.z, w2);
      fma4(acc[rr], xv.w, w3);
    }
  }
#pragma unroll
  for (int rr = 0; rr < 16; ++rr) {
    ((float4*)(xz + (size_t)(row0 + rs + 8 * rr) * K4))[cg] = acc[rr];
  }
}

// ---------------- Kernel B: LSTM scan — one wave per batch, no barriers ----------------
// Column layout (z = [i | f | g | o], 32 each):
//   lane u <32 : kA = u      (i_u),  kB = u+64  (g_u)   -> computes i*g, ships via shfl
//   lane 32+u  : kA = 32+u   (f_u),  kB = 96+u  (o_u)   -> owns c_u, computes h_u
// Gate transcendentals unified: 3 exp + 3 rcp per step for the whole wave.
__device__ __forceinline__ float bcast_(float v, int j) {
  return __uint_as_float(__builtin_amdgcn_readlane(__float_as_uint(v), j));
}

// amdgpu_waves_per_eu(1,1): R3/R4/R6 all showed VGPR_Count pinned at 44-52 — the
// pre-RA scheduler targets ~10 waves/EU occupancy for this tiny kernel (512/10
// ~= 51 regs) and remats/spills the 64 U values into the serial loop. Fixing the
// occupancy RANGE to exactly 1 wave/EU raises the budget to 512 so U stays live.
__global__ __launch_bounds__(64)
__attribute__((amdgpu_waves_per_eu(1, 1)))
void lstm_scan(float* __restrict__ zbuf, const float* __restrict__ U) {
  __shared__ float h_lds[64][32];      // h staging: written per-step, flushed /64 steps
  const int lane = threadIdx.x;        // 0..63
  const int kA = lane;                 // i (lo) / f (hi) column
  const int kB = lane + 64;            // g (lo) / o (hi) column
  const bool hi = (lane >= 32);

  // U columns kA,kB in registers; asm pin makes the values opaque (remat illegal).
  f32x4 Ua[8], Ub[8];
#pragma unroll
  for (int j4 = 0; j4 < 8; ++j4) {
#pragma unroll
    for (int e = 0; e < 4; ++e) {
      Ua[j4][e] = U[(4 * j4 + e) * K4 + kA];
      Ub[j4][e] = U[(4 * j4 + e) * K4 + kB];
    }
  }
  asm volatile("" : "+v"(Ua[0]), "+v"(Ua[1]), "+v"(Ua[2]), "+v"(Ua[3]),
                    "+v"(Ua[4]), "+v"(Ua[5]), "+v"(Ua[6]), "+v"(Ua[7]),
                    "+v"(Ub[0]), "+v"(Ub[1]), "+v"(Ub[2]), "+v"(Ub[3]),
                    "+v"(Ub[4]), "+v"(Ub[5]), "+v"(Ub[6]), "+v"(Ub[7]));

  float* zb = zbuf + (size_t)blockIdx.x * T_ * K4;

  // 4-deep static register prefetch queue for xz
  float qa0 = zb[(size_t)0 * K4 + kA], qb0 = zb[(size_t)0 * K4 + kB];
  float qa1 = zb[(size_t)1 * K4 + kA], qb1 = zb[(size_t)1 * K4 + kB];
  float qa2 = zb[(size_t)2 * K4 + kA], qb2 = zb[(size_t)2 * K4 + kB];
  float qa3 = zb[(size_t)3 * K4 + kA], qb3 = zb[(size_t)3 * K4 + kB];

  float c = 0.f, hval = 0.f;

  auto step = [&](float& qa, float& qb, int t, int tl) {
    const float zAin = qa, zBin = qb;
    const int tc = (tl < T_) ? tl : (T_ - 1);       // clamped loads never consumed
    qa = zb[(size_t)tc * K4 + kA];
    qb = zb[(size_t)tc * K4 + kB];

    // z = xz + h @ U : h broadcast from hi lanes via readlane (SGPR operand)
    float a0 = zAin, a1 = 0.f, a2 = 0.f, a3 = 0.f;
    float b0 = zBin, b1 = 0.f, b2 = 0.f, b3 = 0.f;
#pragma unroll
    for (int j4 = 0; j4 < 8; ++j4) {
      const float h0 = bcast_(hval, 32 + 4 * j4 + 0);
      const float h1 = bcast_(hval, 32 + 4 * j4 + 1);
      const float h2 = bcast_(hval, 32 + 4 * j4 + 2);
      const float h3 = bcast_(hval, 32 + 4 * j4 + 3);
      a0 = fmaf(h0, Ua[j4][0], a0);  b0 = fmaf(h0, Ub[j4][0], b0);
      a1 = fmaf(h1, Ua[j4][1], a1);  b1 = fmaf(h1, Ub[j4][1], b1);
      a2 = fmaf(h2, Ua[j4][2], a2);  b2 = fmaf(h2, Ub[j4][2], b2);
      a3 = fmaf(h3, Ua[j4][3], a3);  b3 = fmaf(h3, Ub[j4][3], b3);
    }
    const float zA = (a0 + a1) + (a2 + a3);         // lo: z_i   hi: z_f
    const float zB = (b0 + b1) + (b2 + b3);         // lo: z_g   hi: z_o

    const float sA = 1.f / (1.f + __expf(-zA));     // lo: i     hi: f
    const float eB = __expf(hi ? -zB : 2.f * zB);
    const float rB = 1.f / (1.f + eB);
    const float gB = hi ? rB : (eB - 1.f) * rB;     // lo: tanh(g)  hi: o

    const float ig  = sA * gB;                      // lo: i*g
    const float igx = __shfl_xor(ig, 32);           // hi receives i*g

    c = fmaf(sA, c, igx);                           // hi: c = f*c + i*g
    const float E2 = __expf(2.f * c);
    const float r2 = 1.f / (1.f + E2);
    hval = gB * ((E2 - 1.f) * r2);                  // hi: h = o * tanh(c)

    if (hi) h_lds[t & 63][lane & 31] = hval;        // stage h (no global store in loop)
  };

  for (int t = 0; t < T_; t += 4) {
    step(qa0, qb0, t + 0, t + 4);
    step(qa1, qb1, t + 1, t + 5);
    step(qa2, qb2, t + 2, t + 6);
    step(qa3, qb3, t + 3, t + 7);

    if ((t & 63) == 60) {
      // flush h rows [t-60, t+3] to zbuf as coalesced dwordx4
      const int t0 = t - 60;
      const int r_ = lane >> 3;        // 0..7
      const int q_ = lane & 7;         // float4 slot 0..7
#pragma unroll
      for (int i = 0; i < 8; ++i) {
        const int r = i * 8 + r_;
        float4 v = *(const float4*)&h_lds[r][q_ * 4];
        *(float4*)&zb[(size_t)(t0 + r) * K4 + q_ * 4] = v;
      }
    }
  }
}

// ---------------- Kernel C: logits = h @ Wd + bd, softmax over V=13 ----------------
__global__ __launch_bounds__(256) void dense_softmax(const float* __restrict__ hbuf,
                                                     const float* __restrict__ Wd,
                                                     const float* __restrict__ bd,
                                                     float* __restrict__ out) {
  __shared__ float4 Wds4[H_ * 4];    // Wd padded [32][16]
  __shared__ float  bds[16];
  if (threadIdx.x < 128) {
    const int j = threadIdx.x >> 2, q = threadIdx.x & 3;
    float4 v = make_float4(0.f, 0.f, 0.f, 0.f);
    const int c0 = q * 4;
    if (c0 + 0 < V_) v.x = Wd[j * V_ + c0 + 0];
    if (c0 + 1 < V_) v.y = Wd[j * V_ + c0 + 1];
    if (c0 + 2 < V_) v.z = Wd[j * V_ + c0 + 2];
    if (c0 + 3 < V_) v.w = Wd[j * V_ + c0 + 3];
    Wds4[j * 4 + q] = v;
  }
  if (threadIdx.x < 16) bds[threadIdx.x] = (threadIdx.x < V_) ? bd[threadIdx.x] : 0.f;
  __syncthreads();

  const int row = blockIdx.x * 256 + threadIdx.x;   // B*T rows, exact grid
  const float4* hr = (const float4*)(hbuf + (size_t)row * K4);  // h = first 32 floats
  float h[H_];
#pragma unroll
  for (int j = 0; j < H_ / 4; ++j) {
    float4 v = hr[j];
    h[4 * j + 0] = v.x; h[4 * j + 1] = v.y; h[4 * j + 2] = v.z; h[4 * j + 3] = v.w;
  }
  float4 acc[4];
#pragma unroll
  for (int q = 0; q < 4; ++q)
    acc[q] = make_float4(bds[4 * q], bds[4 * q + 1], bds[4 * q + 2], bds[4 * q + 3]);
#pragma unroll
  for (int j = 0; j < H_; ++j) {
    const float hj = h[j];
    fma4(acc[0], hj, Wds4[j * 4 + 0]);
    fma4(acc[1], hj, Wds4[j * 4 + 1]);
    fma4(acc[2], hj, Wds4[j * 4 + 2]);
    fma4(acc[3], hj, Wds4[j * 4 + 3]);
  }
  float lg[16];
#pragma unroll
  for (int q = 0; q < 4; ++q) {
    lg[4 * q + 0] = acc[q].x; lg[4 * q + 1] = acc[q].y;
    lg[4 * q + 2] = acc[q].z; lg[4 * q + 3] = acc[q].w;
  }
  float m = lg[0];
#pragma unroll
  for (int v = 1; v < V_; ++v) m = fmaxf(m, lg[v]);
  float s = 0.f;
#pragma unroll
  for (int v = 0; v < V_; ++v) { float e = __expf(lg[v] - m); lg[v] = e; s += e; }
  const float r = 1.f / s;
  float* orow = out + (size_t)row * V_;
#pragma unroll
  for (int v = 0; v < V_; ++v) orow[v] = lg[v] * r;
}

extern "C" void kernel_launch(void* const* d_in, const int* in_sizes, int n_in,
                              void* d_out, int out_size, void* d_ws, size_t ws_size,
                              hipStream_t stream) {
  const float* x  = (const float*)d_in[0];
  const float* W  = (const float*)d_in[1];
  const float* U  = (const float*)d_in[2];
  const float* b  = (const float*)d_in[3];
  const float* Wd = (const float*)d_in[4];
  const float* bd = (const float*)d_in[5];
  float* out  = (float*)d_out;
  float* zbuf = (float*)d_ws;                   // [B,T,128] fp32 = 134 MB

  xz_gemm<<<(B_ * T_) / 128, 256, 0, stream>>>(x, W, b, zbuf);
  lstm_scan<<<B_, 64, 0, stream>>>(zbuf, U);
  dense_softmax<<<(B_ * T_) / 256, 256, 0, stream>>>(zbuf, Wd, bd, out);
}

// Round 8
// 443.905 us; speedup vs baseline: 1.0343x; 1.0343x over previous
//
#include <hip/hip_runtime.h>

#define B_ 256
#define T_ 1024
#define F_ 64
#define H_ 32
#define V_ 13
#define K4 128   // 4*H

typedef float f32x4 __attribute__((ext_vector_type(4)));

__device__ __forceinline__ void fma4(float4& acc, float s, const float4& wv) {
  acc.x = fmaf(s, wv.x, acc.x);
  acc.y = fmaf(s, wv.y, acc.y);
  acc.z = fmaf(s, wv.z, acc.z);
  acc.w = fmaf(s, wv.w, acc.w);
}

// ---------------- Kernel A: xz = x @ W + b  ([B*T,64] @ [64,128]) ----------------
__global__ __launch_bounds__(256, 2) void xz_gemm(const float* __restrict__ x,
                                                  const float* __restrict__ W,
                                                  const float* __restrict__ bias,
                                                  float* __restrict__ xz) {
  __shared__ float4 Ws4[F_ * 32];    // W[f][0..127] as 32 float4 per f   (32 KB)
  __shared__ float4 Xs4[128 * 16];   // x[r][0..63]  as 16 float4 per row (32 KB)

  const float4* W4 = (const float4*)W;
  for (int i = threadIdx.x; i < F_ * 32; i += 256) Ws4[i] = W4[i];
  const int row0 = blockIdx.x * 128;
  const float4* X4 = (const float4*)(x + (size_t)row0 * F_);
  for (int i = threadIdx.x; i < 128 * 16; i += 256) Xs4[i] = X4[i];
  __syncthreads();

  const int cg = threadIdx.x & 31;   // column group: cols 4*cg .. 4*cg+3
  const int rs = threadIdx.x >> 5;   // row slot 0..7; rows rs + 8*rr
  const float4 bv = ((const float4*)bias)[cg];

  float4 acc[16];
#pragma unroll
  for (int rr = 0; rr < 16; ++rr) acc[rr] = bv;

#pragma unroll
  for (int fg = 0; fg < 16; ++fg) {                 // 4 f-values per iteration
    float4 w0 = Ws4[(4 * fg + 0) * 32 + cg];
    float4 w1 = Ws4[(4 * fg + 1) * 32 + cg];
    float4 w2 = Ws4[(4 * fg + 2) * 32 + cg];
    float4 w3 = Ws4[(4 * fg + 3) * 32 + cg];
#pragma unroll
    for (int rr = 0; rr < 16; ++rr) {
      float4 xv = Xs4[(rs + 8 * rr) * 16 + fg];
      fma4(acc[rr], xv.x, w0);
      fma4(acc[rr], xv.y, w1);
      fma4(acc[rr], xv.z, w2);
      fma4(acc[rr], xv.w, w3);
    }
  }
#pragma unroll
  for (int rr = 0; rr < 16; ++rr) {
    ((float4*)(xz + (size_t)(row0 + rs + 8 * rr) * K4))[cg] = acc[rr];
  }
}

// ---------------- Kernel B: LSTM scan — 4 waves/block, one batch per wave ----------------
// Column layout (z = [i | f | g | o], 32 each):
//   lane u <32 : kA = u      (i_u),  kB = u+64  (g_u)   -> computes i*g, ships via permlane
//   lane 32+u  : kA = 32+u   (f_u),  kB = 96+u  (o_u)   -> owns c_u, computes h_u
// R7 changes: (1) 64 blocks x 4 waves (guarantees 1 block/CU; waves on separate SIMDs;
// rules out 2-blocks-on-one-CU serialization of R6's 256x1-wave launch).
// (2) lo->hi i*g handoff via v_permlane32_swap_b32 (VALU, ~6cyc) instead of
// __shfl_xor -> ds_bpermute (LDS latency ~120cyc + lgkmcnt on the serial chain).
__device__ __forceinline__ float bcast_(float v, int j) {
  return __uint_as_float(__builtin_amdgcn_readlane(__float_as_uint(v), j));
}

__global__ __launch_bounds__(256)
__attribute__((amdgpu_waves_per_eu(1, 1)))
void lstm_scan(float* __restrict__ zbuf, const float* __restrict__ U) {
  __shared__ float h_lds[4][64][32];   // per-wave h staging, flushed every 64 steps
  const int lane = threadIdx.x & 63;
  const int wv   = threadIdx.x >> 6;   // wave id 0..3
  const int batch = blockIdx.x * 4 + wv;
  const int kA = lane;                 // i (lo) / f (hi) column
  const int kB = lane + 64;            // g (lo) / o (hi) column
  const bool hi = (lane >= 32);

  // U columns kA,kB in registers; asm pin keeps them live (VGPR=132 verified in R7).
  f32x4 Ua[8], Ub[8];
#pragma unroll
  for (int j4 = 0; j4 < 8; ++j4) {
#pragma unroll
    for (int e = 0; e < 4; ++e) {
      Ua[j4][e] = U[(4 * j4 + e) * K4 + kA];
      Ub[j4][e] = U[(4 * j4 + e) * K4 + kB];
    }
  }
  asm volatile("" : "+v"(Ua[0]), "+v"(Ua[1]), "+v"(Ua[2]), "+v"(Ua[3]),
                    "+v"(Ua[4]), "+v"(Ua[5]), "+v"(Ua[6]), "+v"(Ua[7]),
                    "+v"(Ub[0]), "+v"(Ub[1]), "+v"(Ub[2]), "+v"(Ub[3]),
                    "+v"(Ub[4]), "+v"(Ub[5]), "+v"(Ub[6]), "+v"(Ub[7]));

  float* zb = zbuf + (size_t)batch * T_ * K4;

  // 4-deep static register prefetch queue for xz
  float qa0 = zb[(size_t)0 * K4 + kA], qb0 = zb[(size_t)0 * K4 + kB];
  float qa1 = zb[(size_t)1 * K4 + kA], qb1 = zb[(size_t)1 * K4 + kB];
  float qa2 = zb[(size_t)2 * K4 + kA], qb2 = zb[(size_t)2 * K4 + kB];
  float qa3 = zb[(size_t)3 * K4 + kA], qb3 = zb[(size_t)3 * K4 + kB];

  float c = 0.f, hval = 0.f;

  auto step = [&](float& qa, float& qb, int t, int tl) {
    const float zAin = qa, zBin = qb;
    const int tc = (tl < T_) ? tl : (T_ - 1);       // clamped loads never consumed
    qa = zb[(size_t)tc * K4 + kA];
    qb = zb[(size_t)tc * K4 + kB];

    // z = xz + h @ U : h broadcast from hi lanes via readlane (SGPR operand)
    float a0 = zAin, a1 = 0.f, a2 = 0.f, a3 = 0.f;
    float b0 = zBin, b1 = 0.f, b2 = 0.f, b3 = 0.f;
#pragma unroll
    for (int j4 = 0; j4 < 8; ++j4) {
      const float h0 = bcast_(hval, 32 + 4 * j4 + 0);
      const float h1 = bcast_(hval, 32 + 4 * j4 + 1);
      const float h2 = bcast_(hval, 32 + 4 * j4 + 2);
      const float h3 = bcast_(hval, 32 + 4 * j4 + 3);
      a0 = fmaf(h0, Ua[j4][0], a0);  b0 = fmaf(h0, Ub[j4][0], b0);
      a1 = fmaf(h1, Ua[j4][1], a1);  b1 = fmaf(h1, Ub[j4][1], b1);
      a2 = fmaf(h2, Ua[j4][2], a2);  b2 = fmaf(h2, Ub[j4][2], b2);
      a3 = fmaf(h3, Ua[j4][3], a3);  b3 = fmaf(h3, Ub[j4][3], b3);
    }
    const float zA = (a0 + a1) + (a2 + a3);         // lo: z_i   hi: z_f
    const float zB = (b0 + b1) + (b2 + b3);         // lo: z_g   hi: z_o

    const float sA = 1.f / (1.f + __expf(-zA));     // lo: i     hi: f
    const float eB = __expf(hi ? -zB : 2.f * zB);
    const float rB = 1.f / (1.f + eB);
    const float gB = hi ? rB : (eB - 1.f) * rB;     // lo: tanh(g)  hi: o

    const float ig = sA * gB;                       // lo: i*g
    // xor-32 handoff in-register: dst.hi <- src.lo (partner's i*g), VALU-only.
    float dst = ig, src = ig;
    asm volatile("v_permlane32_swap_b32 %0, %1" : "+v"(dst), "+v"(src));
    const float igx = dst;                          // hi lanes: partner's i*g

    c = fmaf(sA, c, igx);                           // hi: c = f*c + i*g
    const float E2 = __expf(2.f * c);
    const float r2 = 1.f / (1.f + E2);
    hval = gB * ((E2 - 1.f) * r2);                  // hi: h = o * tanh(c)

    if (hi) h_lds[wv][t & 63][lane & 31] = hval;    // stage h (no global store in loop)
  };

  for (int t = 0; t < T_; t += 4) {
    step(qa0, qb0, t + 0, t + 4);
    step(qa1, qb1, t + 1, t + 5);
    step(qa2, qb2, t + 2, t + 6);
    step(qa3, qb3, t + 3, t + 7);

    if ((t & 63) == 60) {
      // flush h rows [t-60, t+3] to zbuf as coalesced dwordx4 (per-wave slab)
      const int t0 = t - 60;
      const int r_ = lane >> 3;        // 0..7
      const int q_ = lane & 7;         // float4 slot 0..7
#pragma unroll
      for (int i = 0; i < 8; ++i) {
        const int r = i * 8 + r_;
        float4 v = *(const float4*)&h_lds[wv][r][q_ * 4];
        *(float4*)&zb[(size_t)(t0 + r) * K4 + q_ * 4] = v;
      }
    }
  }
}

// ---------------- Kernel C: logits = h @ Wd + bd, softmax over V=13 ----------------
__global__ __launch_bounds__(256) void dense_softmax(const float* __restrict__ hbuf,
                                                     const float* __restrict__ Wd,
                                                     const float* __restrict__ bd,
                                                     float* __restrict__ out) {
  __shared__ float4 Wds4[H_ * 4];    // Wd padded [32][16]
  __shared__ float  bds[16];
  if (threadIdx.x < 128) {
    const int j = threadIdx.x >> 2, q = threadIdx.x & 3;
    float4 v = make_float4(0.f, 0.f, 0.f, 0.f);
    const int c0 = q * 4;
    if (c0 + 0 < V_) v.x = Wd[j * V_ + c0 + 0];
    if (c0 + 1 < V_) v.y = Wd[j * V_ + c0 + 1];
    if (c0 + 2 < V_) v.z = Wd[j * V_ + c0 + 2];
    if (c0 + 3 < V_) v.w = Wd[j * V_ + c0 + 3];
    Wds4[j * 4 + q] = v;
  }
  if (threadIdx.x < 16) bds[threadIdx.x] = (threadIdx.x < V_) ? bd[threadIdx.x] : 0.f;
  __syncthreads();

  const int row = blockIdx.x * 256 + threadIdx.x;   // B*T rows, exact grid
  const float4* hr = (const float4*)(hbuf + (size_t)row * K4);  // h = first 32 floats
  float h[H_];
#pragma unroll
  for (int j = 0; j < H_ / 4; ++j) {
    float4 v = hr[j];
    h[4 * j + 0] = v.x; h[4 * j + 1] = v.y; h[4 * j + 2] = v.z; h[4 * j + 3] = v.w;
  }
  float4 acc[4];
#pragma unroll
  for (int q = 0; q < 4; ++q)
    acc[q] = make_float4(bds[4 * q], bds[4 * q + 1], bds[4 * q + 2], bds[4 * q + 3]);
#pragma unroll
  for (int j = 0; j < H_; ++j) {
    const float hj = h[j];
    fma4(acc[0], hj, Wds4[j * 4 + 0]);
    fma4(acc[1], hj, Wds4[j * 4 + 1]);
    fma4(acc[2], hj, Wds4[j * 4 + 2]);
    fma4(acc[3], hj, Wds4[j * 4 + 3]);
  }
  float lg[16];
#pragma unroll
  for (int q = 0; q < 4; ++q) {
    lg[4 * q + 0] = acc[q].x; lg[4 * q + 1] = acc[q].y;
    lg[4 * q + 2] = acc[q].z; lg[4 * q + 3] = acc[q].w;
  }
  float m = lg[0];
#pragma unroll
  for (int v = 1; v < V_; ++v) m = fmaxf(m, lg[v]);
  float s = 0.f;
#pragma unroll
  for (int v = 0; v < V_; ++v) { float e = __expf(lg[v] - m); lg[v] = e; s += e; }
  const float r = 1.f / s;
  float* orow = out + (size_t)row * V_;
#pragma unroll
  for (int v = 0; v < V_; ++v) orow[v] = lg[v] * r;
}

extern "C" void kernel_launch(void* const* d_in, const int* in_sizes, int n_in,
                              void* d_out, int out_size, void* d_ws, size_t ws_size,
                              hipStream_t stream) {
  const float* x  = (const float*)d_in[0];
  const float* W  = (const float*)d_in[1];
  const float* U  = (const float*)d_in[2];
  const float* b  = (const float*)d_in[3];
  const float* Wd = (const float*)d_in[4];
  const float* bd = (const float*)d_in[5];
  float* out  = (float*)d_out;
  float* zbuf = (float*)d_ws;                   // [B,T,128] fp32 = 134 MB

  xz_gemm<<<(B_ * T_) / 128, 256, 0, stream>>>(x, W, b, zbuf);
  lstm_scan<<<B_ / 4, 256, 0, stream>>>(zbuf, U);
  dense_softmax<<<(B_ * T_) / 256, 256, 0, stream>>>(zbuf, Wd, bd, out);
}